// Round 1
// baseline (2876.341 us; speedup 1.0000x reference)
//
#include <hip/hip_runtime.h>
#include <math.h>

#define N_ATOMS 40000
#define N_EDGES 640000
#define NB      128
#define NRBF    20
#define NLAYERS 3
#define CUTOFF  5.0f
#define DELTA   (CUTOFF / 19.0f)
#define RBF_COEFF (-0.5f / (DELTA * DELTA))
#define LN2F    0.69314718055994531f
#define EPB     1024   // edges per block (multiple of 16)

__device__ __forceinline__ float ssp_f(float x) {
    // softplus(x) - log(2), numerically stable
    return fmaxf(x, 0.f) + __logf(1.f + __expf(-fabsf(x))) - LN2F;
}

__global__ __launch_bounds__(256) void k_zero(float* __restrict__ p, int n) {
    int i = blockIdx.x * blockDim.x + threadIdx.x;
    if (i < n) p[i] = 0.f;
}

__global__ __launch_bounds__(256) void k_embed(const int* __restrict__ z,
                                               const float* __restrict__ emb,
                                               float* __restrict__ x) {
    int idx = blockIdx.x * blockDim.x + threadIdx.x;
    if (idx < N_ATOMS * NB) {
        int n = idx >> 7, f = idx & 127;
        x[idx] = emb[z[n] * NB + f];
    }
}

// H[r][f] = sum_k X[r][k] * W[k][f]   (no bias). 16 rows per block, 256 thr.
__global__ __launch_bounds__(256) void k_gemm_rows(const float* __restrict__ X,
                                                   const float* __restrict__ W,
                                                   float* __restrict__ H) {
    __shared__ float xs[16 * NB];
    int tid = threadIdx.x;
    int s2 = tid >> 7, f = tid & 127;
    int row0 = blockIdx.x * 16;
    const float4* Xv = (const float4*)(X + (size_t)row0 * NB);
    float4* xsv = (float4*)xs;
    for (int i = tid; i < 16 * NB / 4; i += 256) xsv[i] = Xv[i];
    __syncthreads();
    float acc[8] = {0.f,0.f,0.f,0.f,0.f,0.f,0.f,0.f};
    #pragma unroll 4
    for (int k = 0; k < NB; ++k) {
        float wv = W[k * NB + f];
        #pragma unroll
        for (int j = 0; j < 8; ++j) acc[j] += xs[(s2 * 8 + j) * NB + k] * wv;
    }
    #pragma unroll
    for (int j = 0; j < 8; ++j) {
        int r = row0 + s2 * 8 + j;
        H[(size_t)r * NB + f] = acc[j];
    }
}

// X[r][f] += ssp(AGG@W1 + b1)@W2 + b2   (fused two GEMMs), 16 rows/block.
__global__ __launch_bounds__(256) void k_out(const float* __restrict__ AGG,
                                             const float* __restrict__ W1,
                                             const float* __restrict__ b1,
                                             const float* __restrict__ W2,
                                             const float* __restrict__ b2,
                                             float* __restrict__ X) {
    __shared__ float as_[16 * NB];
    __shared__ float ts[16 * NB];
    int tid = threadIdx.x;
    int s2 = tid >> 7, f = tid & 127;
    int row0 = blockIdx.x * 16;
    const float4* Av = (const float4*)(AGG + (size_t)row0 * NB);
    float4* asv = (float4*)as_;
    for (int i = tid; i < 16 * NB / 4; i += 256) asv[i] = Av[i];
    __syncthreads();
    float rb1 = b1[f];
    float acc[8] = {0.f,0.f,0.f,0.f,0.f,0.f,0.f,0.f};
    #pragma unroll 4
    for (int k = 0; k < NB; ++k) {
        float wv = W1[k * NB + f];
        #pragma unroll
        for (int j = 0; j < 8; ++j) acc[j] += as_[(s2 * 8 + j) * NB + k] * wv;
    }
    #pragma unroll
    for (int j = 0; j < 8; ++j)
        ts[(s2 * 8 + j) * NB + f] = ssp_f(acc[j] + rb1);
    __syncthreads();
    float rb2 = b2[f];
    float acc2[8] = {0.f,0.f,0.f,0.f,0.f,0.f,0.f,0.f};
    #pragma unroll 4
    for (int k = 0; k < NB; ++k) {
        float wv = W2[k * NB + f];
        #pragma unroll
        for (int j = 0; j < 8; ++j) acc2[j] += ts[(s2 * 8 + j) * NB + k] * wv;
    }
    #pragma unroll
    for (int j = 0; j < 8; ++j) {
        int r = row0 + s2 * 8 + j;
        X[(size_t)r * NB + f] += acc2[j] + rb2;
    }
}

// Fused edge kernel: RBF -> ssp(f@W1+b1) -> @W2+b2 -> *rcut -> h[j]*Wij -> segment-sum.
// 256 threads = 2 slots x 128 features. Each slot streams a contiguous half of the
// block's edge chunk, 8 edges per group, running accumulator + boundary atomicAdd.
__global__ __launch_bounds__(256) void k_edge(const float* __restrict__ r_ij,
                                              const int* __restrict__ idx_i,
                                              const int* __restrict__ idx_j,
                                              const float* __restrict__ H,
                                              const float* __restrict__ W1,
                                              const float* __restrict__ b1,
                                              const float* __restrict__ W2,
                                              const float* __restrict__ b2,
                                              float* __restrict__ AGG) {
    __shared__ float d_lds[16];
    __shared__ float rc_lds[16];
    __shared__ float rbf_lds[16][NRBF];
    __shared__ float w_lds[16 * NB];

    int tid = threadIdx.x;
    int s2 = tid >> 7, f = tid & 127;
    int e0 = blockIdx.x * EPB;
    const int half = EPB / 2;

    // preload W1 column f and biases into registers
    float w1c[NRBF];
    #pragma unroll
    for (int r = 0; r < NRBF; ++r) w1c[r] = W1[r * NB + f];
    float rb1 = b1[f], rb2 = b2[f];

    float acc = 0.f;
    int cur_i = -1;

    const int ngroups = half / 8;
    for (int g = 0; g < ngroups; ++g) {
        // phase 0a: 16 threads compute d and cutoff for this group's 16 edges
        if (tid < 16) {
            int sl = tid >> 3;
            int e = e0 + sl * half + g * 8 + (tid & 7);
            float xx = r_ij[e * 3 + 0];
            float yy = r_ij[e * 3 + 1];
            float zz = r_ij[e * 3 + 2];
            float d = sqrtf(xx * xx + yy * yy + zz * zz);
            d_lds[tid] = d;
            float rc = 0.5f * (__cosf(d * ((float)M_PI / CUTOFF)) + 1.f);
            rc_lds[tid] = (d < CUTOFF) ? rc : 0.f;
        }
        __syncthreads();
        // phase 0b: RBF expansion (16 edges x 20 basis)
        {
            int el = tid & 15;
            int rr = tid >> 4;           // 0..15
            float d = d_lds[el];
            float dr = d - rr * DELTA;
            rbf_lds[el][rr] = __expf(RBF_COEFF * dr * dr);
            if (rr < 4) {
                int r2 = 16 + rr;
                float dr2 = d - r2 * DELTA;
                rbf_lds[el][r2] = __expf(RBF_COEFF * dr2 * dr2);
            }
        }
        __syncthreads();
        // phase 2: w = ssp(rbf @ W1 + b1) for this slot's 8 edges
        #pragma unroll
        for (int j = 0; j < 8; ++j) {
            int el = s2 * 8 + j;
            float a = rb1;
            #pragma unroll
            for (int r = 0; r < NRBF; ++r) a += rbf_lds[el][r] * w1c[r];
            w_lds[el * NB + f] = ssp_f(a);
        }
        __syncthreads();
        // phase 3: wij = w @ W2 (register-blocked over 8 edges)
        float accw[8] = {0.f,0.f,0.f,0.f,0.f,0.f,0.f,0.f};
        #pragma unroll 4
        for (int k = 0; k < NB; ++k) {
            float wv = W2[k * NB + f];
            #pragma unroll
            for (int j = 0; j < 8; ++j) accw[j] += w_lds[(s2 * 8 + j) * NB + k] * wv;
        }
        // epilogue: sequential segment accumulate for this slot's 8 edges
        for (int j = 0; j < 8; ++j) {
            int e = e0 + s2 * half + g * 8 + j;
            int i_a = idx_i[e];
            int j_a = idx_j[e];
            float wij = (accw[j] + rb2) * rc_lds[s2 * 8 + j];
            float hv = H[(size_t)j_a * NB + f];
            if (i_a != cur_i) {
                if (cur_i >= 0) atomicAdd(&AGG[(size_t)cur_i * NB + f], acc);
                acc = 0.f;
                cur_i = i_a;
            }
            acc += hv * wij;
        }
        __syncthreads();   // protect LDS buffers before next group overwrites
    }
    if (cur_i >= 0) atomicAdd(&AGG[(size_t)cur_i * NB + f], acc);
}

extern "C" void kernel_launch(void* const* d_in, const int* in_sizes, int n_in,
                              void* d_out, int out_size, void* d_ws, size_t ws_size,
                              hipStream_t stream) {
    const int*   z    = (const int*)  d_in[0];
    const float* rij  = (const float*)d_in[1];
    const int*   ii   = (const int*)  d_in[2];
    const int*   jj   = (const int*)  d_in[3];
    const float* emb  = (const float*)d_in[4];
    const float* in2f = (const float*)d_in[5];
    const float* fW1  = (const float*)d_in[6];
    const float* fb1  = (const float*)d_in[7];
    const float* fW2  = (const float*)d_in[8];
    const float* fb2  = (const float*)d_in[9];
    const float* oW1  = (const float*)d_in[10];
    const float* ob1  = (const float*)d_in[11];
    const float* oW2  = (const float*)d_in[12];
    const float* ob2  = (const float*)d_in[13];

    float* X   = (float*)d_out;                    // x lives in d_out
    float* H   = (float*)d_ws;                     // [N_ATOMS, NB]
    float* AGG = H + (size_t)N_ATOMS * NB;         // [N_ATOMS, NB]

    const int NXF = N_ATOMS * NB;

    k_embed<<<(NXF + 255) / 256, 256, 0, stream>>>(z, emb, X);

    for (int l = 0; l < NLAYERS; ++l) {
        k_zero<<<(NXF + 255) / 256, 256, 0, stream>>>(AGG, NXF);
        k_gemm_rows<<<N_ATOMS / 16, 256, 0, stream>>>(X, in2f + (size_t)l * NB * NB, H);
        k_edge<<<N_EDGES / EPB, 256, 0, stream>>>(rij, ii, jj, H,
                                                  fW1 + (size_t)l * NRBF * NB,
                                                  fb1 + (size_t)l * NB,
                                                  fW2 + (size_t)l * NB * NB,
                                                  fb2 + (size_t)l * NB,
                                                  AGG);
        k_out<<<N_ATOMS / 16, 256, 0, stream>>>(AGG,
                                                oW1 + (size_t)l * NB * NB,
                                                ob1 + (size_t)l * NB,
                                                oW2 + (size_t)l * NB * NB,
                                                ob2 + (size_t)l * NB,
                                                X);
    }
}

// Round 2
// 571.544 us; speedup vs baseline: 5.0326x; 5.0326x over previous
//
#include <hip/hip_runtime.h>
#include <math.h>

#define N_ATOMS 40000
#define N_EDGES 640000
#define NB      128
#define NRBF    20
#define NLAYERS 3
#define CUTOFF  5.0f
#define DELTA   (CUTOFF / 19.0f)
#define RBF_COEFF (-0.5f / (DELTA * DELTA))
#define LN2F    0.69314718055994531f

#define KTAB    2048                    // lerp intervals over [0, CUTOFF]
#define TSCALE  ((float)KTAB / CUTOFF)
#define EPB     256                     // edges per block (4 waves x 64)

__device__ __forceinline__ float ssp_f(float x) {
    return fmaxf(x, 0.f) + __logf(1.f + __expf(-fabsf(x))) - LN2F;
}

__global__ __launch_bounds__(256) void k_zero(float* __restrict__ p, int n) {
    int i = blockIdx.x * blockDim.x + threadIdx.x;
    if (i < n) p[i] = 0.f;
}

__global__ __launch_bounds__(256) void k_embed(const int* __restrict__ z,
                                               const float* __restrict__ emb,
                                               float* __restrict__ x) {
    int idx = blockIdx.x * blockDim.x + threadIdx.x;
    if (idx < N_ATOMS * NB) {
        int n = idx >> 7, f = idx & 127;
        x[idx] = emb[z[n] * NB + f];
    }
}

__global__ __launch_bounds__(256) void k_dist(const float* __restrict__ r_ij,
                                              float* __restrict__ D) {
    int e = blockIdx.x * blockDim.x + threadIdx.x;
    if (e < N_EDGES) {
        float xx = r_ij[e * 3 + 0];
        float yy = r_ij[e * 3 + 1];
        float zz = r_ij[e * 3 + 2];
        D[e] = sqrtf(xx * xx + yy * yy + zz * zz);
    }
}

// Build Tab[p][f] = g(d_p) = (ssp(rbf(d_p)@W1+b1)@W2+b2) * rcut(d_p), d_p = p*CUTOFF/KTAB.
// Rows p >= KTAB are zero (d >= CUTOFF). Grid = KTAB+2 blocks x 128 threads.
__global__ __launch_bounds__(128) void k_table(const float* __restrict__ W1,
                                               const float* __restrict__ b1,
                                               const float* __restrict__ W2,
                                               const float* __restrict__ b2,
                                               float* __restrict__ Tab) {
    __shared__ float t_lds[NB];
    int p = blockIdx.x, f = threadIdx.x;
    float d = (float)p * (CUTOFF / (float)KTAB);
    if (p >= KTAB) {                       // d >= cutoff: exact zero row
        Tab[(size_t)p * NB + f] = 0.f;
        return;
    }
    // rbf -> ssp(rbf@W1 + b1)
    float a = b1[f];
    #pragma unroll
    for (int r = 0; r < NRBF; ++r) {
        float dr = d - (float)r * DELTA;
        a += __expf(RBF_COEFF * dr * dr) * W1[r * NB + f];
    }
    t_lds[f] = ssp_f(a);
    __syncthreads();
    float w = b2[f];
    #pragma unroll 4
    for (int k = 0; k < NB; ++k) w += t_lds[k] * W2[k * NB + f];
    float rc = 0.5f * (__cosf(d * ((float)M_PI / CUTOFF)) + 1.f);
    Tab[(size_t)p * NB + f] = w * rc;
}

// H[r][f] = sum_k X[r][k] * W[k][f]   (no bias). 16 rows per block, 256 thr.
__global__ __launch_bounds__(256) void k_gemm_rows(const float* __restrict__ X,
                                                   const float* __restrict__ W,
                                                   float* __restrict__ H) {
    __shared__ float xs[16 * NB];
    int tid = threadIdx.x;
    int s2 = tid >> 7, f = tid & 127;
    int row0 = blockIdx.x * 16;
    const float4* Xv = (const float4*)(X + (size_t)row0 * NB);
    float4* xsv = (float4*)xs;
    for (int i = tid; i < 16 * NB / 4; i += 256) xsv[i] = Xv[i];
    __syncthreads();
    float acc[8] = {0.f,0.f,0.f,0.f,0.f,0.f,0.f,0.f};
    #pragma unroll 4
    for (int k = 0; k < NB; ++k) {
        float wv = W[k * NB + f];
        #pragma unroll
        for (int j = 0; j < 8; ++j) acc[j] += xs[(s2 * 8 + j) * NB + k] * wv;
    }
    #pragma unroll
    for (int j = 0; j < 8; ++j) {
        int r = row0 + s2 * 8 + j;
        H[(size_t)r * NB + f] = acc[j];
    }
}

// X[r][f] += ssp(AGG@W1 + b1)@W2 + b2   (fused two GEMMs), 16 rows/block.
__global__ __launch_bounds__(256) void k_out(const float* __restrict__ AGG,
                                             const float* __restrict__ W1,
                                             const float* __restrict__ b1,
                                             const float* __restrict__ W2,
                                             const float* __restrict__ b2,
                                             float* __restrict__ X) {
    __shared__ float as_[16 * NB];
    __shared__ float ts[16 * NB];
    int tid = threadIdx.x;
    int s2 = tid >> 7, f = tid & 127;
    int row0 = blockIdx.x * 16;
    const float4* Av = (const float4*)(AGG + (size_t)row0 * NB);
    float4* asv = (float4*)as_;
    for (int i = tid; i < 16 * NB / 4; i += 256) asv[i] = Av[i];
    __syncthreads();
    float rb1 = b1[f];
    float acc[8] = {0.f,0.f,0.f,0.f,0.f,0.f,0.f,0.f};
    #pragma unroll 4
    for (int k = 0; k < NB; ++k) {
        float wv = W1[k * NB + f];
        #pragma unroll
        for (int j = 0; j < 8; ++j) acc[j] += as_[(s2 * 8 + j) * NB + k] * wv;
    }
    #pragma unroll
    for (int j = 0; j < 8; ++j)
        ts[(s2 * 8 + j) * NB + f] = ssp_f(acc[j] + rb1);
    __syncthreads();
    float rb2 = b2[f];
    float acc2[8] = {0.f,0.f,0.f,0.f,0.f,0.f,0.f,0.f};
    #pragma unroll 4
    for (int k = 0; k < NB; ++k) {
        float wv = W2[k * NB + f];
        #pragma unroll
        for (int j = 0; j < 8; ++j) acc2[j] += ts[(s2 * 8 + j) * NB + k] * wv;
    }
    #pragma unroll
    for (int j = 0; j < 8; ++j) {
        int r = row0 + s2 * 8 + j;
        X[(size_t)r * NB + f] += acc2[j] + rb2;
    }
}

// Edge kernel via table lerp: msg = H[j] * lerp(Tab, d), segment-sum into AGG.
// 1 wave = 64 contiguous edges; lane = feature pair (float2). Lane t preloads
// edge t's (d, i, j) and broadcasts via shfl. Running accumulator + boundary
// atomics exploit sorted idx_i.
__global__ __launch_bounds__(256) void k_edge(const float* __restrict__ D,
                                              const int* __restrict__ idx_i,
                                              const int* __restrict__ idx_j,
                                              const float2* __restrict__ Hv,
                                              const float2* __restrict__ Tabv,
                                              float* __restrict__ AGG) {
    int wave = threadIdx.x >> 6;
    int lane = threadIdx.x & 63;
    int e0 = blockIdx.x * EPB + wave * 64;

    // lane t holds metadata for edge e0+t
    float d_r = D[e0 + lane];
    int   i_r = idx_i[e0 + lane];
    int   j_r = idx_j[e0 + lane];

    float2 acc = {0.f, 0.f};
    int cur = -1;

    for (int t = 0; t < 64; ++t) {
        float d  = __shfl(d_r, t);
        int   ia = __shfl(i_r, t);
        int   ja = __shfl(j_r, t);

        float u = d * TSCALE;
        int   k = (int)u;
        k = (k > KTAB) ? KTAB : k;        // rows >= KTAB are zero -> w = 0
        float fr = u - (float)k;

        float2 t0 = Tabv[(size_t)k * 64 + lane];
        float2 t1 = Tabv[(size_t)(k + 1) * 64 + lane];
        float2 w;
        w.x = fmaf(fr, t1.x - t0.x, t0.x);
        w.y = fmaf(fr, t1.y - t0.y, t0.y);

        float2 h = Hv[(size_t)ja * 64 + lane];

        if (ia != cur) {
            if (cur >= 0) {
                atomicAdd(&AGG[(size_t)cur * NB + 2 * lane],     acc.x);
                atomicAdd(&AGG[(size_t)cur * NB + 2 * lane + 1], acc.y);
            }
            acc.x = 0.f; acc.y = 0.f;
            cur = ia;
        }
        acc.x = fmaf(h.x, w.x, acc.x);
        acc.y = fmaf(h.y, w.y, acc.y);
    }
    if (cur >= 0) {
        atomicAdd(&AGG[(size_t)cur * NB + 2 * lane],     acc.x);
        atomicAdd(&AGG[(size_t)cur * NB + 2 * lane + 1], acc.y);
    }
}

extern "C" void kernel_launch(void* const* d_in, const int* in_sizes, int n_in,
                              void* d_out, int out_size, void* d_ws, size_t ws_size,
                              hipStream_t stream) {
    const int*   z    = (const int*)  d_in[0];
    const float* rij  = (const float*)d_in[1];
    const int*   ii   = (const int*)  d_in[2];
    const int*   jj   = (const int*)  d_in[3];
    const float* emb  = (const float*)d_in[4];
    const float* in2f = (const float*)d_in[5];
    const float* fW1  = (const float*)d_in[6];
    const float* fb1  = (const float*)d_in[7];
    const float* fW2  = (const float*)d_in[8];
    const float* fb2  = (const float*)d_in[9];
    const float* oW1  = (const float*)d_in[10];
    const float* ob1  = (const float*)d_in[11];
    const float* oW2  = (const float*)d_in[12];
    const float* ob2  = (const float*)d_in[13];

    float* X   = (float*)d_out;                        // x lives in d_out
    float* H   = (float*)d_ws;                         // [N_ATOMS, NB]
    float* AGG = H + (size_t)N_ATOMS * NB;             // [N_ATOMS, NB]
    float* D   = AGG + (size_t)N_ATOMS * NB;           // [N_EDGES]
    float* Tab = D + (size_t)N_EDGES;                  // [(KTAB+2), NB]

    const int NXF = N_ATOMS * NB;

    k_embed<<<(NXF + 255) / 256, 256, 0, stream>>>(z, emb, X);
    k_dist<<<(N_EDGES + 255) / 256, 256, 0, stream>>>(rij, D);

    for (int l = 0; l < NLAYERS; ++l) {
        k_zero<<<(NXF + 255) / 256, 256, 0, stream>>>(AGG, NXF);
        k_table<<<KTAB + 2, 128, 0, stream>>>(fW1 + (size_t)l * NRBF * NB,
                                              fb1 + (size_t)l * NB,
                                              fW2 + (size_t)l * NB * NB,
                                              fb2 + (size_t)l * NB,
                                              Tab);
        k_gemm_rows<<<N_ATOMS / 16, 256, 0, stream>>>(X, in2f + (size_t)l * NB * NB, H);
        k_edge<<<N_EDGES / EPB, 256, 0, stream>>>(D, ii, jj,
                                                  (const float2*)H,
                                                  (const float2*)Tab,
                                                  AGG);
        k_out<<<N_ATOMS / 16, 256, 0, stream>>>(AGG,
                                                oW1 + (size_t)l * NB * NB,
                                                ob1 + (size_t)l * NB,
                                                oW2 + (size_t)l * NB * NB,
                                                ob2 + (size_t)l * NB,
                                                X);
    }
}

// Round 3
// 433.369 us; speedup vs baseline: 6.6372x; 1.3188x over previous
//
#include <hip/hip_runtime.h>
#include <math.h>

#define N_ATOMS 40000
#define N_EDGES 640000
#define NB      128
#define NRBF    20
#define NLAYERS 3
#define CUTOFF  5.0f
#define DELTA   (CUTOFF / 19.0f)
#define RBF_COEFF (-0.5f / (DELTA * DELTA))
#define LN2F    0.69314718055994531f

#define KTAB    2048                    // lerp intervals over [0, CUTOFF]
#define TSCALE  ((float)KTAB / CUTOFF)
#define EPB     256                     // edges per block (4 waves x 64)

typedef __attribute__((ext_vector_type(8))) short bf16x8;
typedef __attribute__((ext_vector_type(4))) short bf16x4;
typedef __attribute__((ext_vector_type(4))) float fx4;

__device__ __forceinline__ float ssp_f(float x) {
    return fmaxf(x, 0.f) + __logf(1.f + __expf(-fabsf(x))) - LN2F;
}

// round-to-nearest-even split of fp32 into hi+lo bf16 (as raw short bits)
__device__ __forceinline__ void split_bf16(float x, short& h, short& l) {
    unsigned u = __float_as_uint(x);
    unsigned r = (u + 0x7fffu + ((u >> 16) & 1u)) & 0xffff0000u;
    h = (short)(r >> 16);
    float lf = x - __uint_as_float(r);
    unsigned u2 = __float_as_uint(lf);
    unsigned r2 = u2 + 0x7fffu + ((u2 >> 16) & 1u);
    l = (short)(r2 >> 16);
}

__global__ __launch_bounds__(256) void k_zero(float* __restrict__ p, int n) {
    int i = blockIdx.x * blockDim.x + threadIdx.x;
    if (i < n) p[i] = 0.f;
}

__global__ __launch_bounds__(256) void k_embed(const int* __restrict__ z,
                                               const float* __restrict__ emb,
                                               float* __restrict__ x) {
    int idx = blockIdx.x * blockDim.x + threadIdx.x;
    if (idx < N_ATOMS * NB) {
        int n = idx >> 7, f = idx & 127;
        x[idx] = emb[z[n] * NB + f];
    }
}

__global__ __launch_bounds__(256) void k_dist(const float* __restrict__ r_ij,
                                              float* __restrict__ D) {
    int e = blockIdx.x * blockDim.x + threadIdx.x;
    if (e < N_EDGES) {
        float xx = r_ij[e * 3 + 0];
        float yy = r_ij[e * 3 + 1];
        float zz = r_ij[e * 3 + 2];
        D[e] = sqrtf(xx * xx + yy * yy + zz * zz);
    }
}

// Precompute per-weight LDS images: W^T split into hi/lo bf16, laid out
// [chunk kc][col][klocal ^ ((col&7)<<3)] so GEMM blocks copy chunks linearly.
// 9 blocks: w = layer*3 + which (0=in2f, 1=oW1, 2=oW2).
__global__ __launch_bounds__(256) void k_prep(const float* __restrict__ in2f,
                                              const float* __restrict__ oW1,
                                              const float* __restrict__ oW2,
                                              short* __restrict__ Wimg) {
    int w = blockIdx.x;
    int layer = w / 3, which = w % 3;
    const float* W = (which == 0 ? in2f : which == 1 ? oW1 : oW2)
                     + (size_t)layer * NB * NB;
    short* hi = Wimg + (size_t)w * 32768;
    short* lo = hi + 16384;
    for (int i = threadIdx.x; i < NB * NB; i += 256) {
        int k = i >> 7, col = i & 127;
        short h, l;
        split_bf16(W[i], h, l);
        int kc = k >> 6, kl = k & 63;
        int idx = kc * 8192 + col * 64 + (kl ^ ((col & 7) << 3));
        hi[idx] = h;
        lo[idx] = l;
    }
}

// Build Tab[p][f] = (ssp(rbf(d_p)@W1+b1)@W2+b2) * rcut(d_p).
__global__ __launch_bounds__(128) void k_table(const float* __restrict__ W1,
                                               const float* __restrict__ b1,
                                               const float* __restrict__ W2,
                                               const float* __restrict__ b2,
                                               float* __restrict__ Tab) {
    __shared__ float t_lds[NB];
    int p = blockIdx.x, f = threadIdx.x;
    float d = (float)p * (CUTOFF / (float)KTAB);
    if (p >= KTAB) {
        Tab[(size_t)p * NB + f] = 0.f;
        return;
    }
    float a = b1[f];
    #pragma unroll
    for (int r = 0; r < NRBF; ++r) {
        float dr = d - (float)r * DELTA;
        a += __expf(RBF_COEFF * dr * dr) * W1[r * NB + f];
    }
    t_lds[f] = ssp_f(a);
    __syncthreads();
    float w = b2[f];
    #pragma unroll 4
    for (int k = 0; k < NB; ++k) w += t_lds[k] * W2[k * NB + f];
    float rc = 0.5f * (__cosf(d * ((float)M_PI / CUTOFF)) + 1.f);
    Tab[(size_t)p * NB + f] = w * rc;
}

// Split-bf16 MFMA GEMM: Out = A[40000x128] @ W[128x128] (+bias, +act, +accum).
// MODE 0: Out = A@W         (no bias)
// MODE 1: Out = ssp(A@W+b)
// MODE 2: Out += A@W+b
// Block: 64 rows x 128 cols, 4 waves (wave = 32r x 64c), K chunked by 64.
template<int MODE>
__global__ __launch_bounds__(256) void k_mfma_gemm(const float* __restrict__ A,
                                                   const short* __restrict__ Wimg,
                                                   const float* __restrict__ bias,
                                                   float* __restrict__ Out) {
    __shared__ short Ah[64 * 64], Al[64 * 64];     // 8 KB + 8 KB
    __shared__ short Wh[128 * 64], Wl[128 * 64];   // 16 KB + 16 KB
    int tid = threadIdx.x;
    int wave = tid >> 6, lane = tid & 63;
    int wr = (wave & 1) * 32;          // wave row offset in block
    int wc = (wave >> 1) * 64;         // wave col offset
    int row0 = blockIdx.x * 64;

    fx4 acc[2][4];
    #pragma unroll
    for (int s = 0; s < 2; ++s)
        #pragma unroll
        for (int c = 0; c < 4; ++c)
            acc[s][c] = (fx4){0.f, 0.f, 0.f, 0.f};

    const short* imgh = Wimg;            // [2][8192]
    const short* imgl = Wimg + 16384;

    for (int kc = 0; kc < 2; ++kc) {
        if (kc) __syncthreads();
        // stage A chunk: fp32 -> split bf16, swizzled
        #pragma unroll
        for (int it = 0; it < 4; ++it) {
            int idx4 = tid + it * 256;              // 0..1023
            int r = idx4 >> 4, kq = (idx4 & 15) << 2;
            float4 v = *(const float4*)(A + (size_t)(row0 + r) * NB + kc * 64 + kq);
            bf16x4 hs, ls;
            const float* vf = (const float*)&v;
            #pragma unroll
            for (int j = 0; j < 4; ++j) {
                short h, l;
                split_bf16(vf[j], h, l);
                hs[j] = h; ls[j] = l;
            }
            int wi = r * 64 + (kq ^ ((r & 7) << 3));
            *(bf16x4*)(Ah + wi) = hs;
            *(bf16x4*)(Al + wi) = ls;
        }
        // stage W chunk: plain vectorized copy of pre-swizzled image
        {
            const bf16x8* sh = (const bf16x8*)(imgh + kc * 8192);
            const bf16x8* sl = (const bf16x8*)(imgl + kc * 8192);
            bf16x8* dh = (bf16x8*)Wh;
            bf16x8* dl = (bf16x8*)Wl;
            #pragma unroll
            for (int it = 0; it < 4; ++it) {
                int i = tid + it * 256;             // 0..1023
                dh[i] = sh[i];
                dl[i] = sl[i];
            }
        }
        __syncthreads();
        // compute: 2 K-steps of 32
        #pragma unroll
        for (int ks = 0; ks < 2; ++ks) {
            int kb = ks * 32 + (lane >> 4) * 8;     // lane's k-base (local)
            bf16x8 a_h[2], a_l[2];
            #pragma unroll
            for (int s = 0; s < 2; ++s) {
                int r = wr + s * 16 + (lane & 15);
                int idx = r * 64 + (kb ^ ((r & 7) << 3));
                a_h[s] = *(const bf16x8*)(Ah + idx);
                a_l[s] = *(const bf16x8*)(Al + idx);
            }
            #pragma unroll
            for (int c = 0; c < 4; ++c) {
                int col = wc + c * 16 + (lane & 15);
                int idx = col * 64 + (kb ^ ((col & 7) << 3));
                bf16x8 b_h = *(const bf16x8*)(Wh + idx);
                bf16x8 b_l = *(const bf16x8*)(Wl + idx);
                #pragma unroll
                for (int s = 0; s < 2; ++s) {
                    acc[s][c] = __builtin_amdgcn_mfma_f32_16x16x32_bf16(a_h[s], b_l, acc[s][c], 0, 0, 0);
                    acc[s][c] = __builtin_amdgcn_mfma_f32_16x16x32_bf16(a_l[s], b_h, acc[s][c], 0, 0, 0);
                    acc[s][c] = __builtin_amdgcn_mfma_f32_16x16x32_bf16(a_h[s], b_h, acc[s][c], 0, 0, 0);
                }
            }
        }
    }
    // epilogue: D lane map col = lane&15, row = (lane>>4)*4 + reg
    #pragma unroll
    for (int s = 0; s < 2; ++s) {
        #pragma unroll
        for (int c = 0; c < 4; ++c) {
            int colg = wc + c * 16 + (lane & 15);
            float bv = (MODE > 0) ? bias[colg] : 0.f;
            #pragma unroll
            for (int reg = 0; reg < 4; ++reg) {
                int rowg = row0 + wr + s * 16 + (lane >> 4) * 4 + reg;
                float v = acc[s][c][reg];
                size_t o = (size_t)rowg * NB + colg;
                if (MODE == 0)      Out[o] = v;
                else if (MODE == 1) Out[o] = ssp_f(v + bv);
                else                Out[o] += v + bv;
            }
        }
    }
}

// Edge kernel via table lerp: msg = H[j] * lerp(Tab, d), segment-sum into AGG.
__global__ __launch_bounds__(256) void k_edge(const float* __restrict__ D,
                                              const int* __restrict__ idx_i,
                                              const int* __restrict__ idx_j,
                                              const float2* __restrict__ Hv,
                                              const float2* __restrict__ Tabv,
                                              float* __restrict__ AGG) {
    int wave = threadIdx.x >> 6;
    int lane = threadIdx.x & 63;
    int e0 = blockIdx.x * EPB + wave * 64;

    float d_r = D[e0 + lane];
    int   i_r = idx_i[e0 + lane];
    int   j_r = idx_j[e0 + lane];

    float2 acc = {0.f, 0.f};
    int cur = -1;

    for (int t = 0; t < 64; ++t) {
        float d  = __shfl(d_r, t);
        int   ia = __shfl(i_r, t);
        int   ja = __shfl(j_r, t);

        float u = d * TSCALE;
        int   k = (int)u;
        k = (k > KTAB) ? KTAB : k;
        float fr = u - (float)k;

        float2 t0 = Tabv[(size_t)k * 64 + lane];
        float2 t1 = Tabv[(size_t)(k + 1) * 64 + lane];
        float2 w;
        w.x = fmaf(fr, t1.x - t0.x, t0.x);
        w.y = fmaf(fr, t1.y - t0.y, t0.y);

        float2 h = Hv[(size_t)ja * 64 + lane];

        if (ia != cur) {
            if (cur >= 0) {
                atomicAdd(&AGG[(size_t)cur * NB + 2 * lane],     acc.x);
                atomicAdd(&AGG[(size_t)cur * NB + 2 * lane + 1], acc.y);
            }
            acc.x = 0.f; acc.y = 0.f;
            cur = ia;
        }
        acc.x = fmaf(h.x, w.x, acc.x);
        acc.y = fmaf(h.y, w.y, acc.y);
    }
    if (cur >= 0) {
        atomicAdd(&AGG[(size_t)cur * NB + 2 * lane],     acc.x);
        atomicAdd(&AGG[(size_t)cur * NB + 2 * lane + 1], acc.y);
    }
}

extern "C" void kernel_launch(void* const* d_in, const int* in_sizes, int n_in,
                              void* d_out, int out_size, void* d_ws, size_t ws_size,
                              hipStream_t stream) {
    const int*   z    = (const int*)  d_in[0];
    const float* rij  = (const float*)d_in[1];
    const int*   ii   = (const int*)  d_in[2];
    const int*   jj   = (const int*)  d_in[3];
    const float* emb  = (const float*)d_in[4];
    const float* in2f = (const float*)d_in[5];
    const float* fW1  = (const float*)d_in[6];
    const float* fb1  = (const float*)d_in[7];
    const float* fW2  = (const float*)d_in[8];
    const float* fb2  = (const float*)d_in[9];
    const float* oW1  = (const float*)d_in[10];
    const float* ob1  = (const float*)d_in[11];
    const float* oW2  = (const float*)d_in[12];
    const float* ob2  = (const float*)d_in[13];

    float* X    = (float*)d_out;                       // x lives in d_out
    float* H    = (float*)d_ws;                        // [N_ATOMS, NB] (also T)
    float* AGG  = H + (size_t)N_ATOMS * NB;            // [N_ATOMS, NB]
    float* D    = AGG + (size_t)N_ATOMS * NB;          // [N_EDGES]
    float* Tab  = D + (size_t)N_EDGES;                 // [(KTAB+2), NB]
    short* Wimg = (short*)(Tab + (size_t)(KTAB + 2) * NB);  // 9 x 32768 shorts

    const int NXF = N_ATOMS * NB;

    k_embed<<<(NXF + 255) / 256, 256, 0, stream>>>(z, emb, X);
    k_dist<<<(N_EDGES + 255) / 256, 256, 0, stream>>>(rij, D);
    k_prep<<<9, 256, 0, stream>>>(in2f, oW1, oW2, Wimg);

    for (int l = 0; l < NLAYERS; ++l) {
        const short* img_in2f = Wimg + (size_t)(l * 3 + 0) * 32768;
        const short* img_oW1  = Wimg + (size_t)(l * 3 + 1) * 32768;
        const short* img_oW2  = Wimg + (size_t)(l * 3 + 2) * 32768;

        k_zero<<<(NXF + 255) / 256, 256, 0, stream>>>(AGG, NXF);
        k_table<<<KTAB + 2, 128, 0, stream>>>(fW1 + (size_t)l * NRBF * NB,
                                              fb1 + (size_t)l * NB,
                                              fW2 + (size_t)l * NB * NB,
                                              fb2 + (size_t)l * NB,
                                              Tab);
        // H = X @ in2f
        k_mfma_gemm<0><<<N_ATOMS / 64, 256, 0, stream>>>(X, img_in2f, nullptr, H);
        // AGG = segment_sum(H[j] * g(d))
        k_edge<<<N_EDGES / EPB, 256, 0, stream>>>(D, ii, jj,
                                                  (const float2*)H,
                                                  (const float2*)Tab,
                                                  AGG);
        // T = ssp(AGG @ oW1 + b1)   (T stored in H buffer)
        k_mfma_gemm<1><<<N_ATOMS / 64, 256, 0, stream>>>(AGG, img_oW1,
                                                         ob1 + (size_t)l * NB, H);
        // X += T @ oW2 + b2
        k_mfma_gemm<2><<<N_ATOMS / 64, 256, 0, stream>>>(H, img_oW2,
                                                         ob2 + (size_t)l * NB, X);
    }
}